// Round 1
// baseline (6060.128 us; speedup 1.0000x reference)
//
#include <hip/hip_runtime.h>
#include <math.h>

#define NN 50000
#define NE 1600000
#define DIN 512
#define HH 128
#define DOUT 8
#define EPSBN 1e-5f

// ---------------- degree / dinv ----------------
__global__ void k_init_deg(float* __restrict__ deg) {
    int i = blockIdx.x * 256 + threadIdx.x;
    if (i < NN) deg[i] = 1.0f;   // self-loop
}

__global__ void k_count_deg(const int* __restrict__ dst, float* __restrict__ deg) {
    int e = blockIdx.x * 256 + threadIdx.x;
    if (e < NE) atomicAdd(&deg[dst[e]], 1.0f);
}

__global__ void k_rsqrt(float* __restrict__ deg) {
    int i = blockIdx.x * 256 + threadIdx.x;
    if (i < NN) deg[i] = rsqrtf(deg[i]);
}

// ---------------- tiled fp32 GEMM: C[M][128] = A[M][K] @ B[K][128] ----------------
#define BM 64
#define BN 128
#define BK 16

__global__ __launch_bounds__(256) void k_gemm128(const float* __restrict__ A,
                                                 const float* __restrict__ B,
                                                 float* __restrict__ C,
                                                 int M, int K) {
    __shared__ float As[BM][BK + 4];
    __shared__ float Bs[BK][BN];
    const int tid = threadIdx.x;
    const int m0 = blockIdx.x * BM;
    const int tn = tid & 31;   // 32 col-groups of 4
    const int tm = tid >> 5;   // 8 row-groups of 8
    const int arow = tid >> 2;
    const int acol = (tid & 3) * 4;
    const int brow = tid >> 5;
    const int bcol = (tid & 31) * 4;

    float acc[8][4];
#pragma unroll
    for (int i = 0; i < 8; ++i)
#pragma unroll
        for (int j = 0; j < 4; ++j) acc[i][j] = 0.0f;

    for (int k0 = 0; k0 < K; k0 += BK) {
        int gm = m0 + arow;
        float4 av = make_float4(0.f, 0.f, 0.f, 0.f);
        if (gm < M) av = *(const float4*)(A + (size_t)gm * K + k0 + acol);
        *(float4*)(&As[arow][acol]) = av;
#pragma unroll
        for (int r = 0; r < 2; ++r) {
            int kk = brow + r * 8;
            float4 bv = *(const float4*)(B + (size_t)(k0 + kk) * BN + bcol);
            *(float4*)(&Bs[kk][bcol]) = bv;
        }
        __syncthreads();
#pragma unroll
        for (int kk = 0; kk < BK; ++kk) {
            float4 bv = *(const float4*)(&Bs[kk][tn * 4]);
            float b0 = bv.x, b1 = bv.y, b2 = bv.z, b3 = bv.w;
            float a[8];
#pragma unroll
            for (int i = 0; i < 8; ++i) a[i] = As[tm * 8 + i][kk];
#pragma unroll
            for (int i = 0; i < 8; ++i) {
                acc[i][0] = fmaf(a[i], b0, acc[i][0]);
                acc[i][1] = fmaf(a[i], b1, acc[i][1]);
                acc[i][2] = fmaf(a[i], b2, acc[i][2]);
                acc[i][3] = fmaf(a[i], b3, acc[i][3]);
            }
        }
        __syncthreads();
    }
#pragma unroll
    for (int i = 0; i < 8; ++i) {
        int gm = m0 + tm * 8 + i;
        if (gm < M) {
            float4 v = make_float4(acc[i][0], acc[i][1], acc[i][2], acc[i][3]);
            *(float4*)(C + (size_t)gm * BN + tn * 4) = v;
        }
    }
}

// ---------------- small GEMM: C[M][8] = A[M][128] @ W[128][8] ----------------
__global__ __launch_bounds__(256) void k_gemm8(const float* __restrict__ A,
                                               const float* __restrict__ W,
                                               float* __restrict__ C, int M) {
    __shared__ float Ws[128 * 8];
    int tid = threadIdx.x;
    for (int i = tid; i < 128 * 8; i += 256) Ws[i] = W[i];
    __syncthreads();
    int m = blockIdx.x * 32 + (tid >> 3);
    int n = tid & 7;
    if (m >= M) return;
    const float* a = A + (size_t)m * 128;
    float s = 0.0f;
#pragma unroll
    for (int k = 0; k < 128; k += 4) {
        float4 av = *(const float4*)(a + k);
        s = fmaf(av.x, Ws[(k + 0) * 8 + n], s);
        s = fmaf(av.y, Ws[(k + 1) * 8 + n], s);
        s = fmaf(av.z, Ws[(k + 2) * 8 + n], s);
        s = fmaf(av.w, Ws[(k + 3) * 8 + n], s);
    }
    C[(size_t)m * 8 + n] = s;
}

// ---------------- self-loop init: h[i][c] = t[i][c]*dinv[i]^2 + bias[c] ----------------
__global__ void k_selfloop(const float* __restrict__ t, const float* __restrict__ dinv,
                           const float* __restrict__ bias, float* __restrict__ h,
                           int n, int cols) {
    int idx = blockIdx.x * 256 + threadIdx.x;
    int q = cols >> 2;
    int total = n * q;
    if (idx >= total) return;
    int row = idx / q;
    int cc = (idx - row * q) * 4;
    float w = dinv[row];
    w *= w;
    float4 v = *(const float4*)(t + (size_t)row * cols + cc);
    float4 b = *(const float4*)(bias + cc);
    float4 o;
    o.x = fmaf(v.x, w, b.x);
    o.y = fmaf(v.y, w, b.y);
    o.z = fmaf(v.z, w, b.z);
    o.w = fmaf(v.w, w, b.w);
    *(float4*)(h + (size_t)row * cols + cc) = o;
}

// ---------------- edge scatter (cols=128): 32 lanes per edge ----------------
__global__ __launch_bounds__(256) void k_scatter128(const float* __restrict__ t,
                                                    const int* __restrict__ src,
                                                    const int* __restrict__ dst,
                                                    const float* __restrict__ dinv,
                                                    float* __restrict__ h) {
    int gtid = blockIdx.x * 256 + threadIdx.x;
    int e = gtid >> 5;
    if (e >= NE) return;
    int c = (gtid & 31) * 4;
    int s = src[e], d = dst[e];
    float w = dinv[s] * dinv[d];
    float4 v = *(const float4*)(t + (size_t)s * 128 + c);
    float* out = h + (size_t)d * 128 + c;
    atomicAdd(out + 0, v.x * w);
    atomicAdd(out + 1, v.y * w);
    atomicAdd(out + 2, v.z * w);
    atomicAdd(out + 3, v.w * w);
}

// ---------------- edge scatter (cols=8): 2 lanes per edge ----------------
__global__ __launch_bounds__(256) void k_scatter8(const float* __restrict__ t,
                                                  const int* __restrict__ src,
                                                  const int* __restrict__ dst,
                                                  const float* __restrict__ dinv,
                                                  float* __restrict__ h) {
    int gtid = blockIdx.x * 256 + threadIdx.x;
    int e = gtid >> 1;
    if (e >= NE) return;
    int c = (gtid & 1) * 4;
    int s = src[e], d = dst[e];
    float w = dinv[s] * dinv[d];
    float4 v = *(const float4*)(t + (size_t)s * 8 + c);
    float* out = h + (size_t)d * 8 + c;
    atomicAdd(out + 0, v.x * w);
    atomicAdd(out + 1, v.y * w);
    atomicAdd(out + 2, v.z * w);
    atomicAdd(out + 3, v.w * w);
}

// ---------------- BN stats ----------------
__global__ void k_zero_stats(float* __restrict__ s) {
    s[threadIdx.x] = 0.0f;  // 256 floats: sums[128] + sumsq[128]
}

__global__ __launch_bounds__(256) void k_bnstats(const float* __restrict__ h,
                                                 float* __restrict__ sums,
                                                 float* __restrict__ sumsq) {
    int c4 = (threadIdx.x & 31) * 4;
    int rg = threadIdx.x >> 5;  // 0..7
    float s1x = 0, s1y = 0, s1z = 0, s1w = 0;
    float s2x = 0, s2y = 0, s2z = 0, s2w = 0;
    for (int r = blockIdx.x * 8 + rg; r < NN; r += gridDim.x * 8) {
        float4 v = *(const float4*)(h + (size_t)r * 128 + c4);
        s1x += v.x; s1y += v.y; s1z += v.z; s1w += v.w;
        s2x = fmaf(v.x, v.x, s2x);
        s2y = fmaf(v.y, v.y, s2y);
        s2z = fmaf(v.z, v.z, s2z);
        s2w = fmaf(v.w, v.w, s2w);
    }
    __shared__ float l1[256][4];
    __shared__ float l2[256][4];
    l1[threadIdx.x][0] = s1x; l1[threadIdx.x][1] = s1y;
    l1[threadIdx.x][2] = s1z; l1[threadIdx.x][3] = s1w;
    l2[threadIdx.x][0] = s2x; l2[threadIdx.x][1] = s2y;
    l2[threadIdx.x][2] = s2z; l2[threadIdx.x][3] = s2w;
    __syncthreads();
    if (rg == 0) {
        int lane = threadIdx.x & 31;
#pragma unroll
        for (int g = 1; g < 8; ++g) {
            int o = g * 32 + lane;
            s1x += l1[o][0]; s1y += l1[o][1]; s1z += l1[o][2]; s1w += l1[o][3];
            s2x += l2[o][0]; s2y += l2[o][1]; s2z += l2[o][2]; s2w += l2[o][3];
        }
        atomicAdd(&sums[c4 + 0], s1x);
        atomicAdd(&sums[c4 + 1], s1y);
        atomicAdd(&sums[c4 + 2], s1z);
        atomicAdd(&sums[c4 + 3], s1w);
        atomicAdd(&sumsq[c4 + 0], s2x);
        atomicAdd(&sumsq[c4 + 1], s2y);
        atomicAdd(&sumsq[c4 + 2], s2z);
        atomicAdd(&sumsq[c4 + 3], s2w);
    }
}

// ---------------- BN apply + ReLU ----------------
__global__ void k_bnrelu(float* __restrict__ h, const float* __restrict__ sums,
                         const float* __restrict__ sumsq, const float* __restrict__ g,
                         const float* __restrict__ beta) {
    int idx = blockIdx.x * 256 + threadIdx.x;
    if (idx >= NN * 32) return;
    int row = idx >> 5;
    int c4 = (idx & 31) * 4;
    const float invn = 1.0f / (float)NN;
    float4 v = *(const float4*)(h + (size_t)row * 128 + c4);
    float o[4];
    float vv[4] = {v.x, v.y, v.z, v.w};
#pragma unroll
    for (int j = 0; j < 4; ++j) {
        int c = c4 + j;
        float mu = sums[c] * invn;
        float var = fmaf(-mu, mu, sumsq[c] * invn);
        float sc = g[c] * rsqrtf(var + EPSBN);
        float sh = fmaf(-mu, sc, beta[c]);
        o[j] = fmaxf(fmaf(vv[j], sc, sh), 0.0f);
    }
    float4 ov = make_float4(o[0], o[1], o[2], o[3]);
    *(float4*)(h + (size_t)row * 128 + c4) = ov;
}

// ---------------- log_softmax over 8 classes ----------------
__global__ void k_logsoftmax(const float* __restrict__ h, float* __restrict__ out) {
    int m = blockIdx.x * 256 + threadIdx.x;
    if (m >= NN) return;
    float4 a = *(const float4*)(h + (size_t)m * 8);
    float4 b = *(const float4*)(h + (size_t)m * 8 + 4);
    float v[8] = {a.x, a.y, a.z, a.w, b.x, b.y, b.z, b.w};
    float mx = v[0];
#pragma unroll
    for (int j = 1; j < 8; ++j) mx = fmaxf(mx, v[j]);
    float se = 0.0f;
#pragma unroll
    for (int j = 0; j < 8; ++j) se += expf(v[j] - mx);
    float lse = logf(se) + mx;
#pragma unroll
    for (int j = 0; j < 8; ++j) v[j] -= lse;
    float4 oa = make_float4(v[0], v[1], v[2], v[3]);
    float4 ob = make_float4(v[4], v[5], v[6], v[7]);
    *(float4*)(out + (size_t)m * 8) = oa;
    *(float4*)(out + (size_t)m * 8 + 4) = ob;
}

extern "C" void kernel_launch(void* const* d_in, const int* in_sizes, int n_in,
                              void* d_out, int out_size, void* d_ws, size_t ws_size,
                              hipStream_t stream) {
    const float* x     = (const float*)d_in[0];
    const int*   eidx  = (const int*)d_in[1];
    const float* W1    = (const float*)d_in[2];
    const float* b1    = (const float*)d_in[3];
    const float* W2    = (const float*)d_in[4];
    const float* b2    = (const float*)d_in[5];
    const float* W3    = (const float*)d_in[6];
    const float* b3    = (const float*)d_in[7];
    const float* g1    = (const float*)d_in[8];
    const float* beta1 = (const float*)d_in[9];
    const float* g2    = (const float*)d_in[10];
    const float* beta2 = (const float*)d_in[11];
    float* out = (float*)d_out;

    const int* src = eidx;
    const int* dst = eidx + NE;

    float* ws   = (float*)d_ws;
    float* dinv = ws;                    // 50000 (rounded to 51200)
    float* A    = ws + 51200;            // N*128
    float* Bf   = A + (size_t)NN * 128;  // N*128
    float* C    = Bf + (size_t)NN * 128; // N*8 (rounded to 409600)
    float* D    = C + 409600;            // N*8
    float* st   = D + 409600;            // 256 floats: sums | sumsq

    // degree / dinv
    k_init_deg<<<(NN + 255) / 256, 256, 0, stream>>>(dinv);
    k_count_deg<<<(NE + 255) / 256, 256, 0, stream>>>(dst, dinv);
    k_rsqrt<<<(NN + 255) / 256, 256, 0, stream>>>(dinv);

    // ---- layer 1 ----
    k_gemm128<<<(NN + BM - 1) / BM, 256, 0, stream>>>(x, W1, A, NN, DIN);
    k_selfloop<<<(NN * 32 + 255) / 256, 256, 0, stream>>>(A, dinv, b1, Bf, NN, 128);
    k_scatter128<<<NE / 8, 256, 0, stream>>>(A, src, dst, dinv, Bf);
    k_zero_stats<<<1, 256, 0, stream>>>(st);
    k_bnstats<<<512, 256, 0, stream>>>(Bf, st, st + 128);
    k_bnrelu<<<(NN * 32 + 255) / 256, 256, 0, stream>>>(Bf, st, st + 128, g1, beta1);

    // ---- layer 2 ----
    k_gemm128<<<(NN + BM - 1) / BM, 256, 0, stream>>>(Bf, W2, A, NN, HH);
    k_selfloop<<<(NN * 32 + 255) / 256, 256, 0, stream>>>(A, dinv, b2, Bf, NN, 128);
    k_scatter128<<<NE / 8, 256, 0, stream>>>(A, src, dst, dinv, Bf);
    k_zero_stats<<<1, 256, 0, stream>>>(st);
    k_bnstats<<<512, 256, 0, stream>>>(Bf, st, st + 128);
    k_bnrelu<<<(NN * 32 + 255) / 256, 256, 0, stream>>>(Bf, st, st + 128, g2, beta2);

    // ---- layer 3 ----
    k_gemm8<<<(NN + 31) / 32, 256, 0, stream>>>(Bf, W3, C, NN);
    k_selfloop<<<(NN * 2 + 255) / 256, 256, 0, stream>>>(C, dinv, b3, D, NN, 8);
    k_scatter8<<<NE * 2 / 256, 256, 0, stream>>>(C, src, dst, dinv, D);
    k_logsoftmax<<<(NN + 255) / 256, 256, 0, stream>>>(D, out);
}

// Round 2
// 862.826 us; speedup vs baseline: 7.0236x; 7.0236x over previous
//
#include <hip/hip_runtime.h>
#include <math.h>

#define NN 50000
#define NE 1600000
#define DIN 512
#define HH 128
#define DOUT 8
#define EPSBN 1e-5f

// ---------------- degree count (int) ----------------
__global__ void k_zero_deg(int* __restrict__ degi) {
    int i = blockIdx.x * 256 + threadIdx.x;
    if (i < NN) degi[i] = 0;
}

__global__ void k_count_deg(const int* __restrict__ dst, int* __restrict__ degi) {
    int e = blockIdx.x * 256 + threadIdx.x;
    if (e < NE) atomicAdd(&degi[dst[e]], 1);
}

__global__ void k_dinv(const int* __restrict__ degi, float* __restrict__ dinv) {
    int i = blockIdx.x * 256 + threadIdx.x;
    if (i < NN) dinv[i] = rsqrtf((float)(degi[i] + 1));
}

// ---------------- exclusive scan over NN degrees (single block) ----------------
#define SCAN_CHUNK 196  // 256*196 = 50176 >= NN

__global__ __launch_bounds__(256) void k_scan(const int* __restrict__ degi,
                                              int* __restrict__ rowptr,
                                              int* __restrict__ cursor) {
    __shared__ int ps[256];
    int t = threadIdx.x;
    int beg = t * SCAN_CHUNK;
    int end = beg + SCAN_CHUNK;
    if (end > NN) end = NN;
    int s = 0;
    for (int i = beg; i < end; ++i) s += degi[i];
    ps[t] = s;
    __syncthreads();
    for (int off = 1; off < 256; off <<= 1) {
        int v = (t >= off) ? ps[t - off] : 0;
        __syncthreads();
        ps[t] += v;
        __syncthreads();
    }
    int run = (t == 0) ? 0 : ps[t - 1];
    for (int i = beg; i < end; ++i) {
        rowptr[i] = run;
        cursor[i] = run;
        run += degi[i];
    }
    if (t == 255) rowptr[NN] = run;
}

// ---------------- CSR fill ----------------
__global__ void k_fill(const int* __restrict__ src, const int* __restrict__ dst,
                       int* __restrict__ cursor, int* __restrict__ csr_src) {
    int e = blockIdx.x * 256 + threadIdx.x;
    if (e < NE) {
        int d = dst[e];
        int pos = atomicAdd(&cursor[d], 1);
        csr_src[pos] = src[e];
    }
}

// ---------------- tiled fp32 GEMM: C[M][128] = A[M][K] @ B[K][128] ----------------
#define BM 64
#define BN 128
#define BK 16

__global__ __launch_bounds__(256) void k_gemm128(const float* __restrict__ A,
                                                 const float* __restrict__ B,
                                                 float* __restrict__ C,
                                                 int M, int K) {
    __shared__ float As[BM][BK + 4];
    __shared__ float Bs[BK][BN];
    const int tid = threadIdx.x;
    const int m0 = blockIdx.x * BM;
    const int tn = tid & 31;
    const int tm = tid >> 5;
    const int arow = tid >> 2;
    const int acol = (tid & 3) * 4;
    const int brow = tid >> 5;
    const int bcol = (tid & 31) * 4;

    float acc[8][4];
#pragma unroll
    for (int i = 0; i < 8; ++i)
#pragma unroll
        for (int j = 0; j < 4; ++j) acc[i][j] = 0.0f;

    for (int k0 = 0; k0 < K; k0 += BK) {
        int gm = m0 + arow;
        float4 av = make_float4(0.f, 0.f, 0.f, 0.f);
        if (gm < M) av = *(const float4*)(A + (size_t)gm * K + k0 + acol);
        *(float4*)(&As[arow][acol]) = av;
#pragma unroll
        for (int r = 0; r < 2; ++r) {
            int kk = brow + r * 8;
            float4 bv = *(const float4*)(B + (size_t)(k0 + kk) * BN + bcol);
            *(float4*)(&Bs[kk][bcol]) = bv;
        }
        __syncthreads();
#pragma unroll
        for (int kk = 0; kk < BK; ++kk) {
            float4 bv = *(const float4*)(&Bs[kk][tn * 4]);
            float b0 = bv.x, b1 = bv.y, b2 = bv.z, b3 = bv.w;
            float a[8];
#pragma unroll
            for (int i = 0; i < 8; ++i) a[i] = As[tm * 8 + i][kk];
#pragma unroll
            for (int i = 0; i < 8; ++i) {
                acc[i][0] = fmaf(a[i], b0, acc[i][0]);
                acc[i][1] = fmaf(a[i], b1, acc[i][1]);
                acc[i][2] = fmaf(a[i], b2, acc[i][2]);
                acc[i][3] = fmaf(a[i], b3, acc[i][3]);
            }
        }
        __syncthreads();
    }
#pragma unroll
    for (int i = 0; i < 8; ++i) {
        int gm = m0 + tm * 8 + i;
        if (gm < M) {
            float4 v = make_float4(acc[i][0], acc[i][1], acc[i][2], acc[i][3]);
            *(float4*)(C + (size_t)gm * BN + tn * 4) = v;
        }
    }
}

// ---------------- small GEMM: C[M][8] = A[M][128] @ W[128][8] ----------------
__global__ __launch_bounds__(256) void k_gemm8(const float* __restrict__ A,
                                               const float* __restrict__ W,
                                               float* __restrict__ C, int M) {
    __shared__ float Ws[128 * 8];
    int tid = threadIdx.x;
    for (int i = tid; i < 128 * 8; i += 256) Ws[i] = W[i];
    __syncthreads();
    int m = blockIdx.x * 32 + (tid >> 3);
    int n = tid & 7;
    if (m >= M) return;
    const float* a = A + (size_t)m * 128;
    float s = 0.0f;
#pragma unroll
    for (int k = 0; k < 128; k += 4) {
        float4 av = *(const float4*)(a + k);
        s = fmaf(av.x, Ws[(k + 0) * 8 + n], s);
        s = fmaf(av.y, Ws[(k + 1) * 8 + n], s);
        s = fmaf(av.z, Ws[(k + 2) * 8 + n], s);
        s = fmaf(av.w, Ws[(k + 3) * 8 + n], s);
    }
    C[(size_t)m * 8 + n] = s;
}

// ---------------- CSR gather (128 cols): 32 lanes per node ----------------
__global__ __launch_bounds__(256) void k_gather128(const float* __restrict__ t,
                                                   const int* __restrict__ rowptr,
                                                   const int* __restrict__ csr_src,
                                                   const float* __restrict__ dinv,
                                                   const float* __restrict__ bias,
                                                   float* __restrict__ h) {
    int g = (blockIdx.x * 256 + threadIdx.x) >> 5;  // node
    if (g >= NN) return;
    int c = (threadIdx.x & 31) * 4;
    int beg = rowptr[g], end = rowptr[g + 1];
    float dd = dinv[g];
    // self-loop + bias
    float4 sv = *(const float4*)(t + (size_t)g * 128 + c);
    float4 bv = *(const float4*)(bias + c);
    float wself = dd * dd;
    float ax = fmaf(sv.x, wself, bv.x);
    float ay = fmaf(sv.y, wself, bv.y);
    float az = fmaf(sv.z, wself, bv.z);
    float aw = fmaf(sv.w, wself, bv.w);
    int s = (beg < end) ? csr_src[beg] : 0;
    for (int e = beg; e < end; ++e) {
        int s_next = (e + 1 < end) ? csr_src[e + 1] : 0;
        float w = dinv[s] * dd;
        float4 v = *(const float4*)(t + (size_t)s * 128 + c);
        ax = fmaf(v.x, w, ax);
        ay = fmaf(v.y, w, ay);
        az = fmaf(v.z, w, az);
        aw = fmaf(v.w, w, aw);
        s = s_next;
    }
    float4 o = make_float4(ax, ay, az, aw);
    *(float4*)(h + (size_t)g * 128 + c) = o;
}

// ---------------- CSR gather (8 cols) + fused log_softmax ----------------
__global__ __launch_bounds__(256) void k_gather8_lsm(const float* __restrict__ t,
                                                     const int* __restrict__ rowptr,
                                                     const int* __restrict__ csr_src,
                                                     const float* __restrict__ dinv,
                                                     const float* __restrict__ bias,
                                                     float* __restrict__ out) {
    int g = (blockIdx.x * 256 + threadIdx.x) >> 3;  // node
    if (g >= NN) return;
    int c = threadIdx.x & 7;
    int beg = rowptr[g], end = rowptr[g + 1];
    float dd = dinv[g];
    float acc = fmaf(t[(size_t)g * 8 + c], dd * dd, bias[c]);
    int s = (beg < end) ? csr_src[beg] : 0;
    for (int e = beg; e < end; ++e) {
        int s_next = (e + 1 < end) ? csr_src[e + 1] : 0;
        float w = dinv[s] * dd;
        acc = fmaf(t[(size_t)s * 8 + c], w, acc);
        s = s_next;
    }
    // log-softmax across the 8 lanes of this node
    float mx = acc;
#pragma unroll
    for (int m = 1; m < 8; m <<= 1) mx = fmaxf(mx, __shfl_xor(mx, m, 8));
    float ex = expf(acc - mx);
    float se = ex;
#pragma unroll
    for (int m = 1; m < 8; m <<= 1) se += __shfl_xor(se, m, 8);
    out[(size_t)g * 8 + c] = acc - (logf(se) + mx);
}

// ---------------- BN stats ----------------
__global__ void k_zero_stats(float* __restrict__ s) {
    s[threadIdx.x] = 0.0f;  // 256 floats: sums[128] + sumsq[128]
}

__global__ __launch_bounds__(256) void k_bnstats(const float* __restrict__ h,
                                                 float* __restrict__ sums,
                                                 float* __restrict__ sumsq) {
    int c4 = (threadIdx.x & 31) * 4;
    int rg = threadIdx.x >> 5;
    float s1x = 0, s1y = 0, s1z = 0, s1w = 0;
    float s2x = 0, s2y = 0, s2z = 0, s2w = 0;
    for (int r = blockIdx.x * 8 + rg; r < NN; r += gridDim.x * 8) {
        float4 v = *(const float4*)(h + (size_t)r * 128 + c4);
        s1x += v.x; s1y += v.y; s1z += v.z; s1w += v.w;
        s2x = fmaf(v.x, v.x, s2x);
        s2y = fmaf(v.y, v.y, s2y);
        s2z = fmaf(v.z, v.z, s2z);
        s2w = fmaf(v.w, v.w, s2w);
    }
    __shared__ float l1[256][4];
    __shared__ float l2[256][4];
    l1[threadIdx.x][0] = s1x; l1[threadIdx.x][1] = s1y;
    l1[threadIdx.x][2] = s1z; l1[threadIdx.x][3] = s1w;
    l2[threadIdx.x][0] = s2x; l2[threadIdx.x][1] = s2y;
    l2[threadIdx.x][2] = s2z; l2[threadIdx.x][3] = s2w;
    __syncthreads();
    if (rg == 0) {
        int lane = threadIdx.x & 31;
#pragma unroll
        for (int gg = 1; gg < 8; ++gg) {
            int o = gg * 32 + lane;
            s1x += l1[o][0]; s1y += l1[o][1]; s1z += l1[o][2]; s1w += l1[o][3];
            s2x += l2[o][0]; s2y += l2[o][1]; s2z += l2[o][2]; s2w += l2[o][3];
        }
        atomicAdd(&sums[c4 + 0], s1x);
        atomicAdd(&sums[c4 + 1], s1y);
        atomicAdd(&sums[c4 + 2], s1z);
        atomicAdd(&sums[c4 + 3], s1w);
        atomicAdd(&sumsq[c4 + 0], s2x);
        atomicAdd(&sumsq[c4 + 1], s2y);
        atomicAdd(&sumsq[c4 + 2], s2z);
        atomicAdd(&sumsq[c4 + 3], s2w);
    }
}

// ---------------- BN apply + ReLU ----------------
__global__ void k_bnrelu(float* __restrict__ h, const float* __restrict__ sums,
                         const float* __restrict__ sumsq, const float* __restrict__ g,
                         const float* __restrict__ beta) {
    int idx = blockIdx.x * 256 + threadIdx.x;
    if (idx >= NN * 32) return;
    int row = idx >> 5;
    int c4 = (idx & 31) * 4;
    const float invn = 1.0f / (float)NN;
    float4 v = *(const float4*)(h + (size_t)row * 128 + c4);
    float o[4];
    float vv[4] = {v.x, v.y, v.z, v.w};
#pragma unroll
    for (int j = 0; j < 4; ++j) {
        int c = c4 + j;
        float mu = sums[c] * invn;
        float var = fmaf(-mu, mu, sumsq[c] * invn);
        float sc = g[c] * rsqrtf(var + EPSBN);
        float sh = fmaf(-mu, sc, beta[c]);
        o[j] = fmaxf(fmaf(vv[j], sc, sh), 0.0f);
    }
    float4 ov = make_float4(o[0], o[1], o[2], o[3]);
    *(float4*)(h + (size_t)row * 128 + c4) = ov;
}

extern "C" void kernel_launch(void* const* d_in, const int* in_sizes, int n_in,
                              void* d_out, int out_size, void* d_ws, size_t ws_size,
                              hipStream_t stream) {
    const float* x     = (const float*)d_in[0];
    const int*   eidx  = (const int*)d_in[1];
    const float* W1    = (const float*)d_in[2];
    const float* b1    = (const float*)d_in[3];
    const float* W2    = (const float*)d_in[4];
    const float* b2    = (const float*)d_in[5];
    const float* W3    = (const float*)d_in[6];
    const float* b3    = (const float*)d_in[7];
    const float* g1    = (const float*)d_in[8];
    const float* beta1 = (const float*)d_in[9];
    const float* g2    = (const float*)d_in[10];
    const float* beta2 = (const float*)d_in[11];
    float* out = (float*)d_out;

    const int* src = eidx;
    const int* dst = eidx + NE;

    char* ws = (char*)d_ws;
    int*   degi    = (int*)ws;                          ws += 51200 * 4;
    int*   cursor  = (int*)ws;                          ws += 51200 * 4;
    int*   rowptr  = (int*)ws;                          ws += 51200 * 4;
    int*   csr_src = (int*)ws;                          ws += (size_t)NE * 4;
    float* dinv    = (float*)ws;                        ws += 51200 * 4;
    float* A       = (float*)ws;                        ws += (size_t)NN * 128 * 4;
    float* Bf      = (float*)ws;                        ws += (size_t)NN * 128 * 4;
    float* C       = (float*)ws;                        ws += 409600 * 4;
    float* st      = (float*)ws;

    // ---- CSR build + dinv ----
    k_zero_deg<<<(NN + 255) / 256, 256, 0, stream>>>(degi);
    k_count_deg<<<(NE + 255) / 256, 256, 0, stream>>>(dst, degi);
    k_dinv<<<(NN + 255) / 256, 256, 0, stream>>>(degi, dinv);
    k_scan<<<1, 256, 0, stream>>>(degi, rowptr, cursor);
    k_fill<<<(NE + 255) / 256, 256, 0, stream>>>(src, dst, cursor, csr_src);

    // ---- layer 1 ----
    k_gemm128<<<(NN + BM - 1) / BM, 256, 0, stream>>>(x, W1, A, NN, DIN);
    k_gather128<<<(NN * 32 + 255) / 256, 256, 0, stream>>>(A, rowptr, csr_src, dinv, b1, Bf);
    k_zero_stats<<<1, 256, 0, stream>>>(st);
    k_bnstats<<<512, 256, 0, stream>>>(Bf, st, st + 128);
    k_bnrelu<<<(NN * 32 + 255) / 256, 256, 0, stream>>>(Bf, st, st + 128, g1, beta1);

    // ---- layer 2 ----
    k_gemm128<<<(NN + BM - 1) / BM, 256, 0, stream>>>(Bf, W2, A, NN, HH);
    k_gather128<<<(NN * 32 + 255) / 256, 256, 0, stream>>>(A, rowptr, csr_src, dinv, b2, Bf);
    k_zero_stats<<<1, 256, 0, stream>>>(st);
    k_bnstats<<<512, 256, 0, stream>>>(Bf, st, st + 128);
    k_bnrelu<<<(NN * 32 + 255) / 256, 256, 0, stream>>>(Bf, st, st + 128, g2, beta2);

    // ---- layer 3 ----
    k_gemm8<<<(NN + 31) / 32, 256, 0, stream>>>(Bf, W3, C, NN);
    k_gather8_lsm<<<(NN * 8 + 255) / 256, 256, 0, stream>>>(C, rowptr, csr_src, dinv, b3, out);
}